// Round 10
// baseline (260.618 us; speedup 1.0000x reference)
//
#include <hip/hip_runtime.h>
#include <stdint.h>

// ConcatLayer_55654186221983 on MI355X (gfx950). All fp32 I/O.
// B=8, C=128, C2=256, H=W=64, EMB=512, GROUPS=32, EPS=1e-5.
// R10: GN2-apply fused into conv2 staging (kills k_gn2a); gn1t merged into
//      k_prep. 7 -> 5 dispatches.

#define B_   8
#define C_   128
#define C2_  256
#define HW_  4096
#define EMB_ 512
#define EPS_ 1e-5f

typedef int   v16i __attribute__((ext_vector_type(16)));
typedef float v16f __attribute__((ext_vector_type(16)));
typedef short v8s  __attribute__((ext_vector_type(8)));
typedef int   v4i  __attribute__((ext_vector_type(4)));

// LDS tile: 3 rows x 66 cols x (256 data + 16 pad) bytes
#define COLB 272
#define LDSZ (3 * 66 * COLB)

__device__ __forceinline__ float silu(float v) { return v / (1.f + expf(-v)); }
__device__ __forceinline__ unsigned short f2bf(float f) {
    unsigned int x = __float_as_uint(f);
    return (unsigned short)((x + 0x7FFFu + ((x >> 16) & 1u)) >> 16);  // RNE
}
__device__ __forceinline__ int8_t sgn8(float v) {
    return (v > 0.f) ? (int8_t)1 : ((v < 0.f) ? (int8_t)(-1) : (int8_t)0);
}

// ---- mega-prep:
// blocks 0..127    : binary weights + alpha + zero bnS/bnQ/gnS/gnQ
// blocks 128..703  : conv weight relayout
// blocks 704..895  : embedding MLPs (wave per output row)
// blocks 896..1151 : GN1+SiLU -> actA (NHWC bf16), 256 thr per (n,grp)
__global__ __launch_bounds__(256) void k_prep(
    const float* __restrict__ w, int8_t* __restrict__ sgn,
    float* __restrict__ alpha, float* __restrict__ bnS, float* __restrict__ bnQ,
    float* __restrict__ gnS, float* __restrict__ gnQ,
    const float* __restrict__ w1, const float* __restrict__ w2,
    unsigned short* __restrict__ Wc1, unsigned short* __restrict__ Wc2,
    const float* __restrict__ emb,
    const float* __restrict__ ew, const float* __restrict__ ebb,
    const float* __restrict__ m1w, const float* __restrict__ m1b,
    const float* __restrict__ m2w, const float* __restrict__ m2b,
    const float* __restrict__ m3w, const float* __restrict__ m3b,
    float* __restrict__ eo, float* __restrict__ b1,
    float* __restrict__ b2, float* __restrict__ b3,
    const float* __restrict__ cin,
    const float* __restrict__ g1, const float* __restrict__ bb1,
    unsigned short* __restrict__ act) {
    __shared__ float red[256], red2[256];
    __shared__ float s_mu, s_rstd;
    const int blk = blockIdx.x, tid = threadIdx.x;
    if (blk < 128) {
        const int o = blk;
        if (o == 0 && tid < 128) { bnS[tid] = 0.f; bnQ[tid] = 0.f; }
        if (o == 1) { gnS[tid] = 0.f; }
        if (o == 2) { gnQ[tid] = 0.f; }
        const float* wr = w + (size_t)o * (C2_ * 9);
        float s = 0.f;
        for (int i = tid; i < C2_ * 9; i += 256) s += fabsf(wr[i]);
        red[tid] = s;
        __syncthreads();
        for (int st = 128; st > 0; st >>= 1) {
            if (tid < st) red[tid] += red[tid + st];
            __syncthreads();
        }
        if (tid == 0) alpha[o] = red[0] / (float)(C2_ * 9);
        for (int kk = 0; kk < 9; ++kk) {
            float v = wr[tid * 9 + kk];   // tid == ci
            sgn[((size_t)(kk * 16 + (tid >> 4)) * C_ + o) * 16 + (tid & 15)] = sgn8(v);
        }
    } else if (blk < 704) {
        int i = (blk - 128) * 256 + tid;
        int co = i / (C_ * 9);
        int rem = i - co * (C_ * 9);
        int ci = rem / 9, kk = rem - ci * 9;
        size_t d = ((size_t)(kk * 16 + (ci >> 3)) * C_ + co) * 8 + (ci & 7);
        Wc1[d] = f2bf(w1[i]);
        Wc2[d] = f2bf(w2[i]);
    } else if (blk < 896) {
        const int o = (blk - 704) * 4 + (tid >> 6);   // wave-uniform, 0..767
        const int l = tid & 63;
        const float* wv;
        float bias;
        float* dst;
        int dstride;
        if (o < 256)      { wv = ew  + (size_t)o * EMB_;              bias = ebb[o];    dst = eo + o;  dstride = 256; }
        else if (o < 512) { int r = o - 256; wv = m1w + (size_t)r * EMB_; bias = m1b[r]; dst = b1 + r; dstride = 256; }
        else if (o < 640) { int r = o - 512; wv = m2w + (size_t)r * EMB_; bias = m2b[r]; dst = b2 + r; dstride = 128; }
        else              { int r = o - 640; wv = m3w + (size_t)r * EMB_; bias = m3b[r]; dst = b3 + r; dstride = 128; }
        const float4 wa = *(const float4*)(wv + 8 * l);
        const float4 wb = *(const float4*)(wv + 8 * l + 4);
#pragma unroll
        for (int b = 0; b < B_; ++b) {
            const float* s = emb + b * EMB_ + 8 * l;
            float4 sa = *(const float4*)(s);
            float4 sb = *(const float4*)(s + 4);
            float p = wa.x * silu(sa.x) + wa.y * silu(sa.y) + wa.z * silu(sa.z) + wa.w * silu(sa.w) +
                      wb.x * silu(sb.x) + wb.y * silu(sb.y) + wb.z * silu(sb.z) + wb.w * silu(sb.w);
#pragma unroll
            for (int off = 32; off > 0; off >>= 1) p += __shfl_down(p, off, 64);
            if (l == 0) dst[b * dstride] = bias + p;
        }
    } else {
        // GN1 + SiLU -> NHWC bf16
        const int bid = blk - 896;
        const int n = bid >> 5, grp = bid & 31;
        const size_t base = ((size_t)(n * C_ + grp * 4)) << 12;
        float sum = 0.f, sq = 0.f;
        const float4* in4 = (const float4*)(cin + base);
        for (int i = tid; i < 4096; i += 256) {
            float4 v = in4[i];
            sum += v.x + v.y + v.z + v.w;
            sq += v.x * v.x + v.y * v.y + v.z * v.z + v.w * v.w;
        }
        red[tid] = sum; red2[tid] = sq;
        __syncthreads();
        for (int st = 128; st > 0; st >>= 1) {
            if (tid < st) { red[tid] += red[tid + st]; red2[tid] += red2[tid + st]; }
            __syncthreads();
        }
        if (tid == 0) {
            float mu = red[0] * (1.f / 16384.f);
            float var = red2[0] * (1.f / 16384.f) - mu * mu;
            s_mu = mu; s_rstd = rsqrtf(var + EPS_);
        }
        __syncthreads();
        const float mu = s_mu, rstd = s_rstd;
        float gg[4], bbv[4];
#pragma unroll
        for (int j = 0; j < 4; ++j) { gg[j] = g1[grp * 4 + j]; bbv[j] = bb1[grp * 4 + j]; }
        for (int hw = tid; hw < HW_; hw += 256) {
            union { unsigned short u[4]; uint2 v; } pk;
#pragma unroll
            for (int j = 0; j < 4; ++j) {
                float v = cin[base + ((size_t)j << 12) + hw];
                pk.u[j] = f2bf(silu((v - mu) * rstd * gg[j] + bbv[j]));
            }
            *(uint2*)(act + ((size_t)(n * HW_ + hw)) * C_ + grp * 4) = pk.v;
        }
    }
}

// ---- shared LDS row-staging: 3 rows x 64 cols of 256B -> padded cols 1..64 ----
__device__ __forceinline__ void stage_rows(char* lds, const char* rs0,
                                           const char* rs1, const char* rs2) {
    const int tid = threadIdx.x;
    const char* rs[3] = {rs0, rs1, rs2};
    if (tid < 96) {
        int r = tid / 32, q = tid & 31;
        int c = (q >> 4) ? 65 : 0, o = q & 15;
        *(float4*)(lds + (r * 66 + c) * COLB + o * 16) = make_float4(0.f, 0.f, 0.f, 0.f);
    }
#pragma unroll
    for (int u = 0; u < 12; ++u) {
        int idx = u * 256 + tid;
        int r = idx >> 10, rem = idx & 1023;
        int x = rem >> 4, o = rem & 15;
        char* dst = lds + (r * 66 + x + 1) * COLB + o * 16;
        if (rs[r]) *(float4*)dst = *(const float4*)(rs[r] + x * 256 + o * 16);
        else       *(float4*)dst = make_float4(0.f, 0.f, 0.f, 0.f);
    }
}

// ---- conv1: bf16 MFMA implicit-GEMM + fused GN2 stats ----
__global__ __launch_bounds__(256) void k_conv1(const unsigned short* __restrict__ act,
                                               const unsigned short* __restrict__ Wc,
                                               const float* __restrict__ bias,
                                               float* __restrict__ out,
                                               float* __restrict__ gnS,
                                               float* __restrict__ gnQ) {
    __shared__ __align__(16) char lds[LDSZ];
    const int y = blockIdx.x;
    const int n = blockIdx.y;
    const char* base = (const char*)(act + ((size_t)n * 64) * 64 * C_);
    stage_rows(lds,
               (y > 0)  ? base + (size_t)(y - 1) * 16384 : nullptr,
               base + (size_t)y * 16384,
               (y < 63) ? base + (size_t)(y + 1) * 16384 : nullptr);
    __syncthreads();

    const int w = threadIdx.x >> 6;
    const int l = threadIdx.x & 63;
    const int lm = l & 31;
    const int lh = l >> 5;

    v16f acc0, acc1;
#pragma unroll
    for (int i = 0; i < 16; ++i) { acc0[i] = 0.f; acc1[i] = 0.f; }

#pragma unroll
    for (int kk = 0; kk < 9; ++kk) {
        const int r = kk / 3, dx = kk % 3 - 1;
        const char* col0 = lds + (r * 66 + lm + 1 + dx) * COLB + 16 * lh;
        const char* col1 = col0 + 32 * COLB;
        const unsigned short* wbase = Wc + (size_t)(kk * 16 + lh) * C_ * 8 + (32 * w + lm) * 8;
#pragma unroll
        for (int cb = 0; cb < 8; ++cb) {
            v8s a = *(const v8s*)(wbase + (size_t)(2 * cb) * C_ * 8);
            v8s b0 = *(const v8s*)(col0 + 32 * cb);
            v8s b1 = *(const v8s*)(col1 + 32 * cb);
            acc0 = __builtin_amdgcn_mfma_f32_32x32x16_bf16(a, b0, acc0, 0, 0, 0);
            acc1 = __builtin_amdgcn_mfma_f32_32x32x16_bf16(a, b1, acc1, 0, 0, 0);
        }
    }
    float pr[16], qr[16];
#pragma unroll
    for (int r = 0; r < 16; ++r) {
        const int row = (r & 3) + 8 * (r >> 2) + 4 * lh;
        const int co = 32 * w + row;
        const float bv = bias[co];
        const size_t o = (((size_t)n * C_ + co) << 12) + (y << 6);
        float v0 = acc0[r] + bv, v1 = acc1[r] + bv;
        out[o + lm] = v0;
        out[o + 32 + lm] = v1;
        pr[r] = v0 + v1;
        qr[r] = v0 * v0 + v1 * v1;
    }
    __syncthreads();
    float* ldsS = (float*)lds;
    float* ldsQ = (float*)lds + 128;
#pragma unroll
    for (int r = 0; r < 16; ++r) {
        float p = pr[r], q = qr[r];
#pragma unroll
        for (int m = 16; m > 0; m >>= 1) {
            p += __shfl_xor(p, m, 64);
            q += __shfl_xor(q, m, 64);
        }
        if (lm == 0) {
            const int row = (r & 3) + 8 * (r >> 2) + 4 * lh;
            const int co = 32 * w + row;
            ldsS[co] = p;
            ldsQ[co] = q;
        }
    }
    __syncthreads();
    if (threadIdx.x < 32) {
        const int g = threadIdx.x;
        float p = ldsS[4 * g] + ldsS[4 * g + 1] + ldsS[4 * g + 2] + ldsS[4 * g + 3];
        float q = ldsQ[4 * g] + ldsQ[4 * g + 1] + ldsQ[4 * g + 2] + ldsQ[4 * g + 3];
        atomicAdd(&gnS[n * 32 + g], p);
        atomicAdd(&gnQ[n * 32 + g], q);
    }
}

// ---- conv2: fused GN2-apply staging + bf16 MFMA + residual + sign+transpose ----
__global__ __launch_bounds__(256) void k_conv2(const float* __restrict__ y1,
                                               const float* __restrict__ g2,
                                               const float* __restrict__ b2g,
                                               const float* __restrict__ eo,
                                               const float* __restrict__ gnS,
                                               const float* __restrict__ gnQ,
                                               const unsigned short* __restrict__ Wc,
                                               const float* __restrict__ bias,
                                               const float* __restrict__ res,
                                               const float* __restrict__ xin,
                                               const float* __restrict__ b1v,
                                               float* __restrict__ out,
                                               int8_t* __restrict__ S) {
    __shared__ __align__(16) char lds[LDSZ];
    const int y = blockIdx.x;
    const int n = blockIdx.y;
    const int tid = threadIdx.x;

    // staging with on-the-fly GN2+FiLM+SiLU and NCHW->NHWC transpose
    if (tid < 192) {
        const int r = tid / 64, cp = tid & 63;     // cp: channel pair
        const int yy = y + r - 1;
        const int ch0 = 2 * cp;
        char* dst = lds + (r * 66 + 1) * COLB + 2 * ch0;
        if (yy < 0 || yy > 63) {
#pragma unroll
            for (int x = 0; x < 64; ++x) *(int*)(dst + x * COLB) = 0;
        } else {
            const int grp = ch0 >> 2;
            const float mu = gnS[n * 32 + grp] * (1.f / 16384.f);
            const float var = gnQ[n * 32 + grp] * (1.f / 16384.f) - mu * mu;
            const float rstd = rsqrtf(var + EPS_);
            const float gm0 = rstd * g2[ch0],     bt0 = b2g[ch0] - mu * gm0;
            const float gm1 = rstd * g2[ch0 + 1], bt1 = b2g[ch0 + 1] - mu * gm1;
            const float sc0 = 1.f + eo[n * 256 + ch0],     sh0 = eo[n * 256 + 128 + ch0];
            const float sc1 = 1.f + eo[n * 256 + ch0 + 1], sh1 = eo[n * 256 + 128 + ch0 + 1];
            const float* p0 = y1 + (((size_t)(n * C_ + ch0)) << 12) + (yy << 6);
            const float* p1 = p0 + HW_;
#pragma unroll
            for (int xq = 0; xq < 16; ++xq) {
                float4 v0 = *(const float4*)(p0 + 4 * xq);
                float4 v1 = *(const float4*)(p1 + 4 * xq);
                float a0, a1;
                a0 = silu((v0.x * gm0 + bt0) * sc0 + sh0);
                a1 = silu((v1.x * gm1 + bt1) * sc1 + sh1);
                *(int*)(dst + (4 * xq) * COLB) = ((int)f2bf(a1) << 16) | (int)f2bf(a0);
                a0 = silu((v0.y * gm0 + bt0) * sc0 + sh0);
                a1 = silu((v1.y * gm1 + bt1) * sc1 + sh1);
                *(int*)(dst + (4 * xq + 1) * COLB) = ((int)f2bf(a1) << 16) | (int)f2bf(a0);
                a0 = silu((v0.z * gm0 + bt0) * sc0 + sh0);
                a1 = silu((v1.z * gm1 + bt1) * sc1 + sh1);
                *(int*)(dst + (4 * xq + 2) * COLB) = ((int)f2bf(a1) << 16) | (int)f2bf(a0);
                a0 = silu((v0.w * gm0 + bt0) * sc0 + sh0);
                a1 = silu((v1.w * gm1 + bt1) * sc1 + sh1);
                *(int*)(dst + (4 * xq + 3) * COLB) = ((int)f2bf(a1) << 16) | (int)f2bf(a0);
            }
        }
    } else {
        const int t2 = tid - 192;   // 0..63: zero edge columns x=0 and x=65
#pragma unroll
        for (int p = 0; p < 6; ++p) {
            int r = p >> 1, col = (p & 1) ? 65 : 0;
            *(int*)(lds + (r * 66 + col) * COLB + 4 * t2) = 0;
        }
    }
    __syncthreads();

    const int w = tid >> 6;
    const int l = tid & 63;
    const int lm = l & 31;
    const int lh = l >> 5;

    v16f acc0, acc1;
#pragma unroll
    for (int i = 0; i < 16; ++i) { acc0[i] = 0.f; acc1[i] = 0.f; }

#pragma unroll
    for (int kk = 0; kk < 9; ++kk) {
        const int r = kk / 3, dx = kk % 3 - 1;
        const char* col0 = lds + (r * 66 + lm + 1 + dx) * COLB + 16 * lh;
        const char* col1 = col0 + 32 * COLB;
        const unsigned short* wbase = Wc + (size_t)(kk * 16 + lh) * C_ * 8 + (32 * w + lm) * 8;
#pragma unroll
        for (int cb = 0; cb < 8; ++cb) {
            v8s a = *(const v8s*)(wbase + (size_t)(2 * cb) * C_ * 8);
            v8s b0 = *(const v8s*)(col0 + 32 * cb);
            v8s b1 = *(const v8s*)(col1 + 32 * cb);
            acc0 = __builtin_amdgcn_mfma_f32_32x32x16_bf16(a, b0, acc0, 0, 0, 0);
            acc1 = __builtin_amdgcn_mfma_f32_32x32x16_bf16(a, b1, acc1, 0, 0, 0);
        }
    }
    float c2v0[16], c2v1[16];
#pragma unroll
    for (int r = 0; r < 16; ++r) {
        const int row = (r & 3) + 8 * (r >> 2) + 4 * lh;
        const int co = 32 * w + row;
        const float bv = bias[co];
        const size_t o = (((size_t)n * C_ + co) << 12) + (y << 6);
        float v0 = acc0[r] + bv + res[o + lm];
        float v1 = acc1[r] + bv + res[o + 32 + lm];
        out[o + lm] = v0;
        out[o + 32 + lm] = v1;
        c2v0[r] = v0;
        c2v1[r] = v1;
    }

    // fused sign: build S row [64 px][256 ch] in LDS, then store
    __syncthreads();
#pragma unroll
    for (int q = 0; q < 4; ++q) {
        const int co0 = 32 * w + 8 * q + 4 * lh;
        const float b0 = b1v[n * 256 + 128 + co0];
        const float b1b = b1v[n * 256 + 128 + co0 + 1];
        const float b2b = b1v[n * 256 + 128 + co0 + 2];
        const float b3b = b1v[n * 256 + 128 + co0 + 3];
        union { int8_t b[4]; int u; } p0, p1;
        p0.b[0] = sgn8(c2v0[4 * q] + b0);      p1.b[0] = sgn8(c2v1[4 * q] + b0);
        p0.b[1] = sgn8(c2v0[4 * q + 1] + b1b); p1.b[1] = sgn8(c2v1[4 * q + 1] + b1b);
        p0.b[2] = sgn8(c2v0[4 * q + 2] + b2b); p1.b[2] = sgn8(c2v1[4 * q + 2] + b2b);
        p0.b[3] = sgn8(c2v0[4 * q + 3] + b3b); p1.b[3] = sgn8(c2v1[4 * q + 3] + b3b);
        *(int*)(lds + lm * COLB + 128 + co0) = p0.u;
        *(int*)(lds + (32 + lm) * COLB + 128 + co0) = p1.u;
    }
#pragma unroll
    for (int u = 0; u < 8; ++u) {
        int idx = u * 256 + tid;
        int ch = idx >> 4, seg = idx & 15;
        float4 v = *(const float4*)(xin + (((size_t)(n * C_ + ch)) << 12) + (y << 6) + 4 * seg);
        const float bv = b1v[n * 256 + ch];
        lds[(4 * seg) * COLB + ch]     = sgn8(v.x + bv);
        lds[(4 * seg + 1) * COLB + ch] = sgn8(v.y + bv);
        lds[(4 * seg + 2) * COLB + ch] = sgn8(v.z + bv);
        lds[(4 * seg + 3) * COLB + ch] = sgn8(v.w + bv);
    }
    __syncthreads();
    int8_t* Srow = S + ((size_t)(n * HW_) + (y << 6)) * C2_;
#pragma unroll
    for (int u = 0; u < 4; ++u) {
        int idx = u * 256 + tid;
        int px = idx >> 4, c16 = idx & 15;
        *(int4*)(Srow + (size_t)px * C2_ + 16 * c16) = *(const int4*)(lds + px * COLB + 16 * c16);
    }
}

// ---- binary conv: i8 K=32 MFMA implicit GEMM + fused BN stats ----
__global__ __launch_bounds__(256) void k_bconv(const int8_t* __restrict__ S,
                                               const int8_t* __restrict__ Wk,
                                               const float* __restrict__ alpha,
                                               const float* __restrict__ bias,
                                               float* __restrict__ out,
                                               float* __restrict__ bnS,
                                               float* __restrict__ bnQ) {
    __shared__ __align__(16) char lds[LDSZ];
    const int y = blockIdx.x;
    const int n = blockIdx.y;
    const char* base = (const char*)(S + ((size_t)n * 64) * 64 * C2_);
    stage_rows(lds,
               (y > 0)  ? base + (size_t)(y - 1) * 16384 : nullptr,
               base + (size_t)y * 16384,
               (y < 63) ? base + (size_t)(y + 1) * 16384 : nullptr);
    __syncthreads();

    const int w = threadIdx.x >> 6;
    const int l = threadIdx.x & 63;
    const int lm = l & 31;
    const int lh = l >> 5;

    v16i acc0, acc1;
#pragma unroll
    for (int i = 0; i < 16; ++i) { acc0[i] = 0; acc1[i] = 0; }

#pragma unroll
    for (int kk = 0; kk < 9; ++kk) {
        const int r = kk / 3, dx = kk % 3 - 1;
        const char* col0 = lds + (r * 66 + lm + 1 + dx) * COLB + 16 * lh;
        const char* col1 = col0 + 32 * COLB;
        const int8_t* wbase = Wk + (size_t)(kk * 16 + lh) * C_ * 16 + (32 * w + lm) * 16;
#pragma unroll
        for (int s = 0; s < 8; ++s) {
            v4i a = *(const v4i*)(wbase + (size_t)(2 * s) * C_ * 16);
            v4i b0 = *(const v4i*)(col0 + 32 * s);
            v4i b1 = *(const v4i*)(col1 + 32 * s);
            acc0 = __builtin_amdgcn_mfma_i32_32x32x32_i8(a, b0, acc0, 0, 0, 0);
            acc1 = __builtin_amdgcn_mfma_i32_32x32x32_i8(a, b1, acc1, 0, 0, 0);
        }
    }

    float pr[16], qr[16];
#pragma unroll
    for (int r = 0; r < 16; ++r) {
        const int row = (r & 3) + 8 * (r >> 2) + 4 * lh;
        const int co = 32 * w + row;
        const float av = alpha[co], bv = bias[co];
        const size_t o = (((size_t)n * C_ + co) << 12) + (y << 6);
        float v0 = av * (float)acc0[r] + bv;
        float v1 = av * (float)acc1[r] + bv;
        out[o + lm]      = v0;
        out[o + 32 + lm] = v1;
        pr[r] = v0 + v1;
        qr[r] = v0 * v0 + v1 * v1;
    }
    __syncthreads();
    float* ldsS = (float*)lds;
    float* ldsQ = (float*)lds + 128;
#pragma unroll
    for (int r = 0; r < 16; ++r) {
        float p = pr[r], q = qr[r];
#pragma unroll
        for (int m = 16; m > 0; m >>= 1) {
            p += __shfl_xor(p, m, 64);
            q += __shfl_xor(q, m, 64);
        }
        if (lm == 0) {
            const int row = (r & 3) + 8 * (r >> 2) + 4 * lh;
            const int co = 32 * w + row;
            ldsS[co] = p;
            ldsQ[co] = q;
        }
    }
    __syncthreads();
    if (threadIdx.x < 128) {
        atomicAdd(&bnS[threadIdx.x], ldsS[threadIdx.x]);
        atomicAdd(&bnQ[threadIdx.x], ldsQ[threadIdx.x]);
    }
}

// ---- final epilogue, float4 ----
__global__ __launch_bounds__(256) void k_final(const float* __restrict__ y3,
                                               const float* __restrict__ x,
                                               const float* __restrict__ c2,
                                               const float* __restrict__ bnS,
                                               const float* __restrict__ bnQ,
                                               const float* __restrict__ bng,
                                               const float* __restrict__ bnb,
                                               const float* __restrict__ b2v,
                                               const float* __restrict__ pa,
                                               const float* __restrict__ b3v,
                                               float* __restrict__ out) {
    const int idx4 = blockIdx.x * 256 + threadIdx.x;   // < 1,048,576
    const int hw = (idx4 & 1023) * 4;
    const int cb = idx4 >> 10;
    const int co = cb & 127;
    const int n = cb >> 7;
    const float mu = bnS[co] * (1.f / 32768.f);
    const float var = bnQ[co] * (1.f / 32768.f) - mu * mu;
    const float rstd = rsqrtf(var + EPS_);
    const float gm = rstd * bng[co];
    const float bt = bnb[co] - mu * gm;
    const size_t obase = (((size_t)(n * C_ + co)) << 12) + hw;
    float4 v = *(const float4*)(y3 + obase);
    v.x = v.x * gm + bt; v.y = v.y * gm + bt; v.z = v.z * gm + bt; v.w = v.w * gm + bt;

    const int ch0 = 2 * co;
    float4 pA, pB;
    if (co < 64) {
        pA = *(const float4*)(x + (((size_t)(n * C_ + ch0)) << 12) + hw);
        pB = *(const float4*)(x + (((size_t)(n * C_ + ch0 + 1)) << 12) + hw);
    } else {
        int d = ch0 - 128;
        pA = *(const float4*)(c2 + (((size_t)(n * C_ + d)) << 12) + hw);
        pB = *(const float4*)(c2 + (((size_t)(n * C_ + d + 1)) << 12) + hw);
    }
    const float bias2 = b2v[n * 128 + co];
    const float aP = pa[co];
    const float bias3 = b3v[n * 128 + co];
    float4 r;
    float t;
    t = v.x + 0.5f * (pA.x + pB.x) + bias2; t = (t >= 0.f) ? t : aP * t; r.x = t + bias3;
    t = v.y + 0.5f * (pA.y + pB.y) + bias2; t = (t >= 0.f) ? t : aP * t; r.y = t + bias3;
    t = v.z + 0.5f * (pA.z + pB.z) + bias2; t = (t >= 0.f) ? t : aP * t; r.z = t + bias3;
    t = v.w + 0.5f * (pA.w + pB.w) + bias2; t = (t >= 0.f) ? t : aP * t; r.w = t + bias3;
    *(float4*)(out + obase) = r;
}

// ---------------- launch ----------------
extern "C" void kernel_launch(void* const* d_in, const int* in_sizes, int n_in,
                              void* d_out, int out_size, void* d_ws, size_t ws_size,
                              hipStream_t stream) {
    const float* c       = (const float*)d_in[0];
    const float* x       = (const float*)d_in[1];
    const float* emb     = (const float*)d_in[2];
    const float* gn1_g   = (const float*)d_in[3];
    const float* gn1_b   = (const float*)d_in[4];
    const float* conv1_w = (const float*)d_in[5];
    const float* conv1_b = (const float*)d_in[6];
    const float* emb_w   = (const float*)d_in[7];
    const float* emb_b   = (const float*)d_in[8];
    const float* gn2_g   = (const float*)d_in[9];
    const float* gn2_b   = (const float*)d_in[10];
    const float* conv2_w = (const float*)d_in[11];
    const float* conv2_b = (const float*)d_in[12];
    const float* m1_w    = (const float*)d_in[13];
    const float* m1_b    = (const float*)d_in[14];
    const float* bconv_w = (const float*)d_in[15];
    const float* bconv_b = (const float*)d_in[16];
    const float* bn_g    = (const float*)d_in[17];
    const float* bn_b    = (const float*)d_in[18];
    const float* m2_w    = (const float*)d_in[19];
    const float* m2_b    = (const float*)d_in[20];
    const float* prelu_a = (const float*)d_in[21];
    const float* m3_w    = (const float*)d_in[22];
    const float* m3_b    = (const float*)d_in[23];
    float* out = (float*)d_out;

    // ws (~41.2 MB): a_buf 16MB | y_buf 16MB | actA(bf16)/S(i8) aliased 8MB |
    //                sgn 288KB | Wc1 288KB | Wc2 288KB | small vecs
    float* ws = (float*)d_ws;
    const size_t NCHW = (size_t)B_ * C_ * HW_;       // 4,194,304
    float*  a_buf = ws;
    float*  y_buf = ws + NCHW;
    unsigned short* actA = (unsigned short*)(ws + 2 * NCHW);   // 8 MB (NHWC bf16)
    int8_t* S     = (int8_t*)(ws + 2 * NCHW);                  // aliases actA
    int8_t* sgn   = (int8_t*)(ws + 2 * NCHW + NCHW / 2);       // 294912 B
    unsigned short* Wc1 = (unsigned short*)(ws + 2 * NCHW + NCHW / 2 + 73728);
    unsigned short* Wc2 = Wc1 + C_ * C_ * 9;                   // each 294912 B
    float*  alpha = ws + 2 * NCHW + NCHW / 2 + 73728 + 2 * 73728;
    float*  eo    = alpha + 128;
    float*  b1v   = eo + B_ * 256;
    float*  b2v   = b1v + B_ * 256;
    float*  b3v   = b2v + B_ * 128;
    float*  bnS   = b3v + B_ * 128;
    float*  bnQ   = bnS + 128;
    float*  gnS   = bnQ + 128;   // 256
    float*  gnQ   = gnS + 256;   // 256

    k_prep<<<1152, 256, 0, stream>>>(bconv_w, sgn, alpha, bnS, bnQ, gnS, gnQ,
                                     conv1_w, conv2_w, Wc1, Wc2,
                                     emb, emb_w, emb_b, m1_w, m1_b, m2_w, m2_b,
                                     m3_w, m3_b, eo, b1v, b2v, b3v,
                                     c, gn1_g, gn1_b, actA);
    k_conv1<<<dim3(64, B_), 256, 0, stream>>>(actA, Wc1, conv1_b, y_buf, gnS, gnQ);
    k_conv2<<<dim3(64, B_), 256, 0, stream>>>(y_buf, gn2_g, gn2_b, eo, gnS, gnQ,
                                              Wc2, conv2_b, c, x, b1v, a_buf, S); // a_buf = c2
    k_bconv<<<dim3(64, B_), 256, 0, stream>>>(S, sgn, alpha, bconv_b, y_buf, bnS, bnQ); // y_buf = y3
    k_final<<<NCHW / 1024, 256, 0, stream>>>(y_buf, x, a_buf, bnS, bnQ, bn_g, bn_b,
                                             b2v, prelu_a, b3v, out);
}

// Round 12
// 255.873 us; speedup vs baseline: 1.0185x; 1.0185x over previous
//
#include <hip/hip_runtime.h>
#include <stdint.h>

// ConcatLayer_55654186221983 on MI355X (gfx950). All fp32 I/O.
// R12: revert R11's cooperative bconv+final fusion (hipLaunchCooperativeKernel
//      silently no-ops under the harness graph capture -> out never written).
//      Structure = R9 (best known good, 255.4us) + de-aliased S (race fix) +
//      conv2-from-actA (R10 staging fusion stays reverted).

#define B_   8
#define C_   128
#define C2_  256
#define HW_  4096
#define EMB_ 512
#define EPS_ 1e-5f

typedef int   v16i __attribute__((ext_vector_type(16)));
typedef float v16f __attribute__((ext_vector_type(16)));
typedef short v8s  __attribute__((ext_vector_type(8)));
typedef int   v4i  __attribute__((ext_vector_type(4)));

// LDS tile: 3 rows x 66 cols x (256 data + 16 pad) bytes
#define COLB 272
#define LDSZ (3 * 66 * COLB)

__device__ __forceinline__ float silu(float v) { return v / (1.f + expf(-v)); }
__device__ __forceinline__ unsigned short f2bf(float f) {
    unsigned int x = __float_as_uint(f);
    return (unsigned short)((x + 0x7FFFu + ((x >> 16) & 1u)) >> 16);  // RNE
}
__device__ __forceinline__ int8_t sgn8(float v) {
    return (v > 0.f) ? (int8_t)1 : ((v < 0.f) ? (int8_t)(-1) : (int8_t)0);
}

// ---- mega-prep:
// blocks 0..127    : binary weights + alpha + zero bnS/bnQ/gnS/gnQ
// blocks 128..703  : conv weight relayout
// blocks 704..895  : embedding MLPs (wave per output row)
// blocks 896..1151 : GN1+SiLU -> actA (NHWC bf16)
__global__ __launch_bounds__(256) void k_prep(
    const float* __restrict__ w, int8_t* __restrict__ sgn,
    float* __restrict__ alpha, float* __restrict__ bnS, float* __restrict__ bnQ,
    float* __restrict__ gnS, float* __restrict__ gnQ,
    const float* __restrict__ w1, const float* __restrict__ w2,
    unsigned short* __restrict__ Wc1, unsigned short* __restrict__ Wc2,
    const float* __restrict__ emb,
    const float* __restrict__ ew, const float* __restrict__ ebb,
    const float* __restrict__ m1w, const float* __restrict__ m1b,
    const float* __restrict__ m2w, const float* __restrict__ m2b,
    const float* __restrict__ m3w, const float* __restrict__ m3b,
    float* __restrict__ eo, float* __restrict__ b1,
    float* __restrict__ b2, float* __restrict__ b3,
    const float* __restrict__ cin,
    const float* __restrict__ g1, const float* __restrict__ bb1,
    unsigned short* __restrict__ act) {
    __shared__ float red[256], red2[256];
    __shared__ float s_mu, s_rstd;
    const int blk = blockIdx.x, tid = threadIdx.x;
    if (blk < 128) {
        const int o = blk;
        if (o == 0 && tid < 128) { bnS[tid] = 0.f; bnQ[tid] = 0.f; }
        if (o == 1) { gnS[tid] = 0.f; }
        if (o == 2) { gnQ[tid] = 0.f; }
        const float* wr = w + (size_t)o * (C2_ * 9);
        float s = 0.f;
        for (int i = tid; i < C2_ * 9; i += 256) s += fabsf(wr[i]);
        red[tid] = s;
        __syncthreads();
        for (int st = 128; st > 0; st >>= 1) {
            if (tid < st) red[tid] += red[tid + st];
            __syncthreads();
        }
        if (tid == 0) alpha[o] = red[0] / (float)(C2_ * 9);
        for (int kk = 0; kk < 9; ++kk) {
            float v = wr[tid * 9 + kk];   // tid == ci
            sgn[((size_t)(kk * 16 + (tid >> 4)) * C_ + o) * 16 + (tid & 15)] = sgn8(v);
        }
    } else if (blk < 704) {
        int i = (blk - 128) * 256 + tid;
        int co = i / (C_ * 9);
        int rem = i - co * (C_ * 9);
        int ci = rem / 9, kk = rem - ci * 9;
        size_t d = ((size_t)(kk * 16 + (ci >> 3)) * C_ + co) * 8 + (ci & 7);
        Wc1[d] = f2bf(w1[i]);
        Wc2[d] = f2bf(w2[i]);
    } else if (blk < 896) {
        const int o = (blk - 704) * 4 + (tid >> 6);   // wave-uniform, 0..767
        const int l = tid & 63;
        const float* wv;
        float bias;
        float* dst;
        int dstride;
        if (o < 256)      { wv = ew  + (size_t)o * EMB_;              bias = ebb[o];    dst = eo + o;  dstride = 256; }
        else if (o < 512) { int r = o - 256; wv = m1w + (size_t)r * EMB_; bias = m1b[r]; dst = b1 + r; dstride = 256; }
        else if (o < 640) { int r = o - 512; wv = m2w + (size_t)r * EMB_; bias = m2b[r]; dst = b2 + r; dstride = 128; }
        else              { int r = o - 640; wv = m3w + (size_t)r * EMB_; bias = m3b[r]; dst = b3 + r; dstride = 128; }
        const float4 wa = *(const float4*)(wv + 8 * l);
        const float4 wb = *(const float4*)(wv + 8 * l + 4);
#pragma unroll
        for (int b = 0; b < B_; ++b) {
            const float* s = emb + b * EMB_ + 8 * l;
            float4 sa = *(const float4*)(s);
            float4 sb = *(const float4*)(s + 4);
            float p = wa.x * silu(sa.x) + wa.y * silu(sa.y) + wa.z * silu(sa.z) + wa.w * silu(sa.w) +
                      wb.x * silu(sb.x) + wb.y * silu(sb.y) + wb.z * silu(sb.z) + wb.w * silu(sb.w);
#pragma unroll
            for (int off = 32; off > 0; off >>= 1) p += __shfl_down(p, off, 64);
            if (l == 0) dst[b * dstride] = bias + p;
        }
    } else {
        const int bid = blk - 896;
        const int n = bid >> 5, grp = bid & 31;
        const size_t base = ((size_t)(n * C_ + grp * 4)) << 12;
        float sum = 0.f, sq = 0.f;
        const float4* in4 = (const float4*)(cin + base);
        for (int i = tid; i < 4096; i += 256) {
            float4 v = in4[i];
            sum += v.x + v.y + v.z + v.w;
            sq += v.x * v.x + v.y * v.y + v.z * v.z + v.w * v.w;
        }
        red[tid] = sum; red2[tid] = sq;
        __syncthreads();
        for (int st = 128; st > 0; st >>= 1) {
            if (tid < st) { red[tid] += red[tid + st]; red2[tid] += red2[tid + st]; }
            __syncthreads();
        }
        if (tid == 0) {
            float mu = red[0] * (1.f / 16384.f);
            float var = red2[0] * (1.f / 16384.f) - mu * mu;
            s_mu = mu; s_rstd = rsqrtf(var + EPS_);
        }
        __syncthreads();
        const float mu = s_mu, rstd = s_rstd;
        float gg[4], bbv[4];
#pragma unroll
        for (int j = 0; j < 4; ++j) { gg[j] = g1[grp * 4 + j]; bbv[j] = bb1[grp * 4 + j]; }
        for (int hw = tid; hw < HW_; hw += 256) {
            union { unsigned short u[4]; uint2 v; } pk;
#pragma unroll
            for (int j = 0; j < 4; ++j) {
                float v = cin[base + ((size_t)j << 12) + hw];
                pk.u[j] = f2bf(silu((v - mu) * rstd * gg[j] + bbv[j]));
            }
            *(uint2*)(act + ((size_t)(n * HW_ + hw)) * C_ + grp * 4) = pk.v;
        }
    }
}

// ---- GN2 apply-only (+FiLM+SiLU): stats from conv1 epilogue ----
__global__ __launch_bounds__(1024) void k_gn2a(const float* __restrict__ in,
                                               const float* __restrict__ g,
                                               const float* __restrict__ b,
                                               const float* __restrict__ eo,
                                               const float* __restrict__ gnS,
                                               const float* __restrict__ gnQ,
                                               unsigned short* __restrict__ act) {
    const int tid = threadIdx.x;
    const int n = blockIdx.x >> 5, grp = blockIdx.x & 31;
    const size_t base = ((size_t)(n * C_ + grp * 4)) << 12;
    const float mu = gnS[n * 32 + grp] * (1.f / 16384.f);
    const float var = gnQ[n * 32 + grp] * (1.f / 16384.f) - mu * mu;
    const float rstd = rsqrtf(var + EPS_);
    float sc[4], sh[4], gg[4], bb[4];
#pragma unroll
    for (int j = 0; j < 4; ++j) {
        int ch = grp * 4 + j;
        gg[j] = g[ch]; bb[j] = b[ch];
        sc[j] = 1.f + eo[n * 256 + ch];
        sh[j] = eo[n * 256 + 128 + ch];
    }
    for (int hw = tid; hw < HW_; hw += 1024) {
        union { unsigned short u[4]; uint2 v; } pk;
#pragma unroll
        for (int j = 0; j < 4; ++j) {
            float v = in[base + ((size_t)j << 12) + hw];
            float y = ((v - mu) * rstd * gg[j] + bb[j]) * sc[j] + sh[j];
            pk.u[j] = f2bf(silu(y));
        }
        *(uint2*)(act + ((size_t)(n * HW_ + hw)) * C_ + grp * 4) = pk.v;
    }
}

// ---- shared LDS row-staging ----
__device__ __forceinline__ void stage_rows(char* lds, const char* rs0,
                                           const char* rs1, const char* rs2) {
    const int tid = threadIdx.x;
    const char* rs[3] = {rs0, rs1, rs2};
    if (tid < 96) {
        int r = tid / 32, q = tid & 31;
        int c = (q >> 4) ? 65 : 0, o = q & 15;
        *(float4*)(lds + (r * 66 + c) * COLB + o * 16) = make_float4(0.f, 0.f, 0.f, 0.f);
    }
#pragma unroll
    for (int u = 0; u < 12; ++u) {
        int idx = u * 256 + tid;
        int r = idx >> 10, rem = idx & 1023;
        int x = rem >> 4, o = rem & 15;
        char* dst = lds + (r * 66 + x + 1) * COLB + o * 16;
        if (rs[r]) *(float4*)dst = *(const float4*)(rs[r] + x * 256 + o * 16);
        else       *(float4*)dst = make_float4(0.f, 0.f, 0.f, 0.f);
    }
}

// ---- conv1: bf16 MFMA implicit-GEMM + fused GN2 stats ----
__global__ __launch_bounds__(256) void k_conv1(const unsigned short* __restrict__ act,
                                               const unsigned short* __restrict__ Wc,
                                               const float* __restrict__ bias,
                                               float* __restrict__ out,
                                               float* __restrict__ gnS,
                                               float* __restrict__ gnQ) {
    __shared__ __align__(16) char lds[LDSZ];
    const int y = blockIdx.x;
    const int n = blockIdx.y;
    const char* base = (const char*)(act + ((size_t)n * 64) * 64 * C_);
    stage_rows(lds,
               (y > 0)  ? base + (size_t)(y - 1) * 16384 : nullptr,
               base + (size_t)y * 16384,
               (y < 63) ? base + (size_t)(y + 1) * 16384 : nullptr);
    __syncthreads();

    const int w = threadIdx.x >> 6;
    const int l = threadIdx.x & 63;
    const int lm = l & 31;
    const int lh = l >> 5;

    v16f acc0, acc1;
#pragma unroll
    for (int i = 0; i < 16; ++i) { acc0[i] = 0.f; acc1[i] = 0.f; }

#pragma unroll
    for (int kk = 0; kk < 9; ++kk) {
        const int r = kk / 3, dx = kk % 3 - 1;
        const char* col0 = lds + (r * 66 + lm + 1 + dx) * COLB + 16 * lh;
        const char* col1 = col0 + 32 * COLB;
        const unsigned short* wbase = Wc + (size_t)(kk * 16 + lh) * C_ * 8 + (32 * w + lm) * 8;
#pragma unroll
        for (int cb = 0; cb < 8; ++cb) {
            v8s a = *(const v8s*)(wbase + (size_t)(2 * cb) * C_ * 8);
            v8s b0 = *(const v8s*)(col0 + 32 * cb);
            v8s b1 = *(const v8s*)(col1 + 32 * cb);
            acc0 = __builtin_amdgcn_mfma_f32_32x32x16_bf16(a, b0, acc0, 0, 0, 0);
            acc1 = __builtin_amdgcn_mfma_f32_32x32x16_bf16(a, b1, acc1, 0, 0, 0);
        }
    }
    float pr[16], qr[16];
#pragma unroll
    for (int r = 0; r < 16; ++r) {
        const int row = (r & 3) + 8 * (r >> 2) + 4 * lh;
        const int co = 32 * w + row;
        const float bv = bias[co];
        const size_t o = (((size_t)n * C_ + co) << 12) + (y << 6);
        float v0 = acc0[r] + bv, v1 = acc1[r] + bv;
        out[o + lm] = v0;
        out[o + 32 + lm] = v1;
        pr[r] = v0 + v1;
        qr[r] = v0 * v0 + v1 * v1;
    }
    __syncthreads();
    float* ldsS = (float*)lds;
    float* ldsQ = (float*)lds + 128;
#pragma unroll
    for (int r = 0; r < 16; ++r) {
        float p = pr[r], q = qr[r];
#pragma unroll
        for (int m = 16; m > 0; m >>= 1) {
            p += __shfl_xor(p, m, 64);
            q += __shfl_xor(q, m, 64);
        }
        if (lm == 0) {
            const int row = (r & 3) + 8 * (r >> 2) + 4 * lh;
            const int co = 32 * w + row;
            ldsS[co] = p;
            ldsQ[co] = q;
        }
    }
    __syncthreads();
    if (threadIdx.x < 32) {
        const int g = threadIdx.x;
        float p = ldsS[4 * g] + ldsS[4 * g + 1] + ldsS[4 * g + 2] + ldsS[4 * g + 3];
        float q = ldsQ[4 * g] + ldsQ[4 * g + 1] + ldsQ[4 * g + 2] + ldsQ[4 * g + 3];
        atomicAdd(&gnS[n * 32 + g], p);
        atomicAdd(&gnQ[n * 32 + g], q);
    }
}

// ---- conv2: bf16 MFMA (actA in) + residual + fused sign+transpose ----
__global__ __launch_bounds__(256) void k_conv2(const unsigned short* __restrict__ act,
                                               const unsigned short* __restrict__ Wc,
                                               const float* __restrict__ bias,
                                               const float* __restrict__ res,
                                               const float* __restrict__ xin,
                                               const float* __restrict__ b1v,
                                               float* __restrict__ out,
                                               int8_t* __restrict__ S) {
    __shared__ __align__(16) char lds[LDSZ];
    const int y = blockIdx.x;
    const int n = blockIdx.y;
    const int tid = threadIdx.x;
    const char* base = (const char*)(act + ((size_t)n * 64) * 64 * C_);
    stage_rows(lds,
               (y > 0)  ? base + (size_t)(y - 1) * 16384 : nullptr,
               base + (size_t)y * 16384,
               (y < 63) ? base + (size_t)(y + 1) * 16384 : nullptr);
    __syncthreads();

    const int w = tid >> 6;
    const int l = tid & 63;
    const int lm = l & 31;
    const int lh = l >> 5;

    v16f acc0, acc1;
#pragma unroll
    for (int i = 0; i < 16; ++i) { acc0[i] = 0.f; acc1[i] = 0.f; }

#pragma unroll
    for (int kk = 0; kk < 9; ++kk) {
        const int r = kk / 3, dx = kk % 3 - 1;
        const char* col0 = lds + (r * 66 + lm + 1 + dx) * COLB + 16 * lh;
        const char* col1 = col0 + 32 * COLB;
        const unsigned short* wbase = Wc + (size_t)(kk * 16 + lh) * C_ * 8 + (32 * w + lm) * 8;
#pragma unroll
        for (int cb = 0; cb < 8; ++cb) {
            v8s a = *(const v8s*)(wbase + (size_t)(2 * cb) * C_ * 8);
            v8s b0 = *(const v8s*)(col0 + 32 * cb);
            v8s b1 = *(const v8s*)(col1 + 32 * cb);
            acc0 = __builtin_amdgcn_mfma_f32_32x32x16_bf16(a, b0, acc0, 0, 0, 0);
            acc1 = __builtin_amdgcn_mfma_f32_32x32x16_bf16(a, b1, acc1, 0, 0, 0);
        }
    }
    float c2v0[16], c2v1[16];
#pragma unroll
    for (int r = 0; r < 16; ++r) {
        const int row = (r & 3) + 8 * (r >> 2) + 4 * lh;
        const int co = 32 * w + row;
        const float bv = bias[co];
        const size_t o = (((size_t)n * C_ + co) << 12) + (y << 6);
        float v0 = acc0[r] + bv + res[o + lm];
        float v1 = acc1[r] + bv + res[o + 32 + lm];
        out[o + lm] = v0;
        out[o + 32 + lm] = v1;
        c2v0[r] = v0;
        c2v1[r] = v1;
    }

    // fused sign: build S row [64 px][256 ch] in LDS, then store
    __syncthreads();
#pragma unroll
    for (int q = 0; q < 4; ++q) {
        const int co0 = 32 * w + 8 * q + 4 * lh;
        const float b0 = b1v[n * 256 + 128 + co0];
        const float b1b = b1v[n * 256 + 128 + co0 + 1];
        const float b2b = b1v[n * 256 + 128 + co0 + 2];
        const float b3b = b1v[n * 256 + 128 + co0 + 3];
        union { int8_t b[4]; int u; } p0, p1;
        p0.b[0] = sgn8(c2v0[4 * q] + b0);      p1.b[0] = sgn8(c2v1[4 * q] + b0);
        p0.b[1] = sgn8(c2v0[4 * q + 1] + b1b); p1.b[1] = sgn8(c2v1[4 * q + 1] + b1b);
        p0.b[2] = sgn8(c2v0[4 * q + 2] + b2b); p1.b[2] = sgn8(c2v1[4 * q + 2] + b2b);
        p0.b[3] = sgn8(c2v0[4 * q + 3] + b3b); p1.b[3] = sgn8(c2v1[4 * q + 3] + b3b);
        *(int*)(lds + lm * COLB + 128 + co0) = p0.u;
        *(int*)(lds + (32 + lm) * COLB + 128 + co0) = p1.u;
    }
#pragma unroll
    for (int u = 0; u < 8; ++u) {
        int idx = u * 256 + tid;
        int ch = idx >> 4, seg = idx & 15;
        float4 v = *(const float4*)(xin + (((size_t)(n * C_ + ch)) << 12) + (y << 6) + 4 * seg);
        const float bv = b1v[n * 256 + ch];
        lds[(4 * seg) * COLB + ch]     = sgn8(v.x + bv);
        lds[(4 * seg + 1) * COLB + ch] = sgn8(v.y + bv);
        lds[(4 * seg + 2) * COLB + ch] = sgn8(v.z + bv);
        lds[(4 * seg + 3) * COLB + ch] = sgn8(v.w + bv);
    }
    __syncthreads();
    int8_t* Srow = S + ((size_t)(n * HW_) + (y << 6)) * C2_;
#pragma unroll
    for (int u = 0; u < 4; ++u) {
        int idx = u * 256 + tid;
        int px = idx >> 4, c16 = idx & 15;
        *(int4*)(Srow + (size_t)px * C2_ + 16 * c16) = *(const int4*)(lds + px * COLB + 16 * c16);
    }
}

// ---- binary conv: i8 K=32 MFMA implicit GEMM + fused BN stats ----
__global__ __launch_bounds__(256) void k_bconv(const int8_t* __restrict__ S,
                                               const int8_t* __restrict__ Wk,
                                               const float* __restrict__ alpha,
                                               const float* __restrict__ bias,
                                               float* __restrict__ out,
                                               float* __restrict__ bnS,
                                               float* __restrict__ bnQ) {
    __shared__ __align__(16) char lds[LDSZ];
    const int y = blockIdx.x;
    const int n = blockIdx.y;
    const char* base = (const char*)(S + ((size_t)n * 64) * 64 * C2_);
    stage_rows(lds,
               (y > 0)  ? base + (size_t)(y - 1) * 16384 : nullptr,
               base + (size_t)y * 16384,
               (y < 63) ? base + (size_t)(y + 1) * 16384 : nullptr);
    __syncthreads();

    const int w = threadIdx.x >> 6;
    const int l = threadIdx.x & 63;
    const int lm = l & 31;
    const int lh = l >> 5;

    v16i acc0, acc1;
#pragma unroll
    for (int i = 0; i < 16; ++i) { acc0[i] = 0; acc1[i] = 0; }

#pragma unroll
    for (int kk = 0; kk < 9; ++kk) {
        const int r = kk / 3, dx = kk % 3 - 1;
        const char* col0 = lds + (r * 66 + lm + 1 + dx) * COLB + 16 * lh;
        const char* col1 = col0 + 32 * COLB;
        const int8_t* wbase = Wk + (size_t)(kk * 16 + lh) * C_ * 16 + (32 * w + lm) * 16;
#pragma unroll
        for (int s = 0; s < 8; ++s) {
            v4i a = *(const v4i*)(wbase + (size_t)(2 * s) * C_ * 16);
            v4i b0 = *(const v4i*)(col0 + 32 * s);
            v4i b1 = *(const v4i*)(col1 + 32 * s);
            acc0 = __builtin_amdgcn_mfma_i32_32x32x32_i8(a, b0, acc0, 0, 0, 0);
            acc1 = __builtin_amdgcn_mfma_i32_32x32x32_i8(a, b1, acc1, 0, 0, 0);
        }
    }

    float pr[16], qr[16];
#pragma unroll
    for (int r = 0; r < 16; ++r) {
        const int row = (r & 3) + 8 * (r >> 2) + 4 * lh;
        const int co = 32 * w + row;
        const float av = alpha[co], bv = bias[co];
        const size_t o = (((size_t)n * C_ + co) << 12) + (y << 6);
        float v0 = av * (float)acc0[r] + bv;
        float v1 = av * (float)acc1[r] + bv;
        out[o + lm]      = v0;
        out[o + 32 + lm] = v1;
        pr[r] = v0 + v1;
        qr[r] = v0 * v0 + v1 * v1;
    }
    __syncthreads();
    float* ldsS = (float*)lds;
    float* ldsQ = (float*)lds + 128;
#pragma unroll
    for (int r = 0; r < 16; ++r) {
        float p = pr[r], q = qr[r];
#pragma unroll
        for (int m = 16; m > 0; m >>= 1) {
            p += __shfl_xor(p, m, 64);
            q += __shfl_xor(q, m, 64);
        }
        if (lm == 0) {
            const int row = (r & 3) + 8 * (r >> 2) + 4 * lh;
            const int co = 32 * w + row;
            ldsS[co] = p;
            ldsQ[co] = q;
        }
    }
    __syncthreads();
    if (threadIdx.x < 128) {
        atomicAdd(&bnS[threadIdx.x], ldsS[threadIdx.x]);
        atomicAdd(&bnQ[threadIdx.x], ldsQ[threadIdx.x]);
    }
}

// ---- final epilogue, float4 ----
__global__ __launch_bounds__(256) void k_final(const float* __restrict__ y3,
                                               const float* __restrict__ x,
                                               const float* __restrict__ c2,
                                               const float* __restrict__ bnS,
                                               const float* __restrict__ bnQ,
                                               const float* __restrict__ bng,
                                               const float* __restrict__ bnb,
                                               const float* __restrict__ b2v,
                                               const float* __restrict__ pa,
                                               const float* __restrict__ b3v,
                                               float* __restrict__ out) {
    const int idx4 = blockIdx.x * 256 + threadIdx.x;   // < 1,048,576
    const int hw = (idx4 & 1023) * 4;
    const int cb = idx4 >> 10;
    const int co = cb & 127;
    const int n = cb >> 7;
    const float mu = bnS[co] * (1.f / 32768.f);
    const float var = bnQ[co] * (1.f / 32768.f) - mu * mu;
    const float rstd = rsqrtf(var + EPS_);
    const float gm = rstd * bng[co];
    const float bt = bnb[co] - mu * gm;
    const size_t obase = (((size_t)(n * C_ + co)) << 12) + hw;
    float4 v = *(const float4*)(y3 + obase);
    v.x = v.x * gm + bt; v.y = v.y * gm + bt; v.z = v.z * gm + bt; v.w = v.w * gm + bt;

    const int ch0 = 2 * co;
    float4 pA, pB;
    if (co < 64) {
        pA = *(const float4*)(x + (((size_t)(n * C_ + ch0)) << 12) + hw);
        pB = *(const float4*)(x + (((size_t)(n * C_ + ch0 + 1)) << 12) + hw);
    } else {
        int d = ch0 - 128;
        pA = *(const float4*)(c2 + (((size_t)(n * C_ + d)) << 12) + hw);
        pB = *(const float4*)(c2 + (((size_t)(n * C_ + d + 1)) << 12) + hw);
    }
    const float bias2 = b2v[n * 128 + co];
    const float aP = pa[co];
    const float bias3 = b3v[n * 128 + co];
    float4 r;
    float t;
    t = v.x + 0.5f * (pA.x + pB.x) + bias2; t = (t >= 0.f) ? t : aP * t; r.x = t + bias3;
    t = v.y + 0.5f * (pA.y + pB.y) + bias2; t = (t >= 0.f) ? t : aP * t; r.y = t + bias3;
    t = v.z + 0.5f * (pA.z + pB.z) + bias2; t = (t >= 0.f) ? t : aP * t; r.z = t + bias3;
    t = v.w + 0.5f * (pA.w + pB.w) + bias2; t = (t >= 0.f) ? t : aP * t; r.w = t + bias3;
    *(float4*)(out + obase) = r;
}

// ---------------- launch ----------------
extern "C" void kernel_launch(void* const* d_in, const int* in_sizes, int n_in,
                              void* d_out, int out_size, void* d_ws, size_t ws_size,
                              hipStream_t stream) {
    const float* c       = (const float*)d_in[0];
    const float* x       = (const float*)d_in[1];
    const float* emb     = (const float*)d_in[2];
    const float* gn1_g   = (const float*)d_in[3];
    const float* gn1_b   = (const float*)d_in[4];
    const float* conv1_w = (const float*)d_in[5];
    const float* conv1_b = (const float*)d_in[6];
    const float* emb_w   = (const float*)d_in[7];
    const float* emb_b   = (const float*)d_in[8];
    const float* gn2_g   = (const float*)d_in[9];
    const float* gn2_b   = (const float*)d_in[10];
    const float* conv2_w = (const float*)d_in[11];
    const float* conv2_b = (const float*)d_in[12];
    const float* m1_w    = (const float*)d_in[13];
    const float* m1_b    = (const float*)d_in[14];
    const float* bconv_w = (const float*)d_in[15];
    const float* bconv_b = (const float*)d_in[16];
    const float* bn_g    = (const float*)d_in[17];
    const float* bn_b    = (const float*)d_in[18];
    const float* m2_w    = (const float*)d_in[19];
    const float* m2_b    = (const float*)d_in[20];
    const float* prelu_a = (const float*)d_in[21];
    const float* m3_w    = (const float*)d_in[22];
    const float* m3_b    = (const float*)d_in[23];
    float* out = (float*)d_out;

    // ws (~49 MB): a_buf 16 | y_buf 16 | actA 8 | S 8 (separate) | weights ~1
    float* ws = (float*)d_ws;
    const size_t NCHW = (size_t)B_ * C_ * HW_;       // 4,194,304
    float*  a_buf = ws;                               // c2
    float*  y_buf = ws + NCHW;                        // y1 -> y3
    unsigned short* actA = (unsigned short*)(ws + 2 * NCHW);      // 8 MB
    int8_t* S     = (int8_t*)(ws + 2 * NCHW + NCHW / 2);          // 8 MB separate
    int8_t* sgn   = (int8_t*)(ws + 3 * NCHW);                     // 294912 B
    unsigned short* Wc1 = (unsigned short*)(ws + 3 * NCHW + 73728);
    unsigned short* Wc2 = Wc1 + C_ * C_ * 9;
    float*  alpha = ws + 3 * NCHW + 3 * 73728;
    float*  eo    = alpha + 128;
    float*  b1v   = eo + B_ * 256;
    float*  b2v   = b1v + B_ * 256;
    float*  b3v   = b2v + B_ * 128;
    float*  bnS   = b3v + B_ * 128;
    float*  bnQ   = bnS + 128;
    float*  gnS   = bnQ + 128;   // 256
    float*  gnQ   = gnS + 256;   // 256

    k_prep<<<1152, 256, 0, stream>>>(bconv_w, sgn, alpha, bnS, bnQ, gnS, gnQ,
                                     conv1_w, conv2_w, Wc1, Wc2,
                                     emb, emb_w, emb_b, m1_w, m1_b, m2_w, m2_b,
                                     m3_w, m3_b, eo, b1v, b2v, b3v,
                                     c, gn1_g, gn1_b, actA);
    k_conv1<<<dim3(64, B_), 256, 0, stream>>>(actA, Wc1, conv1_b, y_buf, gnS, gnQ);
    k_gn2a<<<B_ * 32, 1024, 0, stream>>>(y_buf, gn2_g, gn2_b, eo, gnS, gnQ, actA);
    k_conv2<<<dim3(64, B_), 256, 0, stream>>>(actA, Wc2, conv2_b, c, x, b1v, a_buf, S);
    k_bconv<<<dim3(64, B_), 256, 0, stream>>>(S, sgn, alpha, bconv_b, y_buf, bnS, bnQ);
    k_final<<<NCHW / 1024, 256, 0, stream>>>(y_buf, x, a_buf, bnS, bnQ, bn_g, bn_b,
                                             b2v, prelu_a, b3v, out);
}